// Round 12
// baseline (531.979 us; speedup 1.0000x reference)
//
#include <hip/hip_runtime.h>
#include <cmath>

typedef unsigned short u16;
typedef unsigned int u32;
typedef short bf16x8 __attribute__((ext_vector_type(8)));
typedef float f32x4 __attribute__((ext_vector_type(4)));

#define NN 50000      // nodes
#define MP 50048      // padded to 128*391
#define EE 400000     // raw edges
#define ET 450000     // edges + self loops
#define HIDD 256
#define KIN 192       // 3*F
#define LN_EPSF 1e-5f

__device__ __forceinline__ float bf2f(u16 u){ return __uint_as_float(((u32)u)<<16); }
__device__ __forceinline__ u16 f2bf(float f){
  u32 x = __float_as_uint(f);
  u32 r = x + 0x7fffu + ((x>>16)&1u);   // RNE
  return (u16)(r>>16);
}
__device__ __forceinline__ float bflo(u32 v){ return __uint_as_float(v<<16); }
__device__ __forceinline__ float bfhi(u32 v){ return __uint_as_float(v & 0xffff0000u); }
__device__ __forceinline__ u32 pack2(float a, float b){ return (u32)f2bf(a) | ((u32)f2bf(b)<<16); }

__device__ __forceinline__ void dma16(const u16* g, u16* lds){
  __builtin_amdgcn_global_load_lds(
      (const __attribute__((address_space(1))) void*)g,
      (__attribute__((address_space(3))) void*)lds, 16, 0, 0);
}

// ================ merged setup: feats | wt | vmat | degree (partitioned by block) ================
__global__ __launch_bounds__(256) void k_setup(
    const float* __restrict__ x, const float* __restrict__ remb, const int* __restrict__ rid,
    u16* __restrict__ feats,
    const float* __restrict__ ipw, const float* __restrict__ gatw,
    u16* __restrict__ wtin, u16* __restrict__ wtl,
    const float* __restrict__ asrc, const float* __restrict__ adst, u16* __restrict__ vmat,
    const int* __restrict__ ei, int* __restrict__ deg)
{
  int b = blockIdx.x;
  if (b < 12512){
    int e = b*768 + threadIdx.x;
    #pragma unroll
    for (int it=0; it<3; ++it, e+=256){
      int n = e / 192;
      int c = e - n*192;
      if (n >= MP) break;
      float v = 0.f;
      if (n < NN){
        if (c < 64){
          v = x[n*64 + c];
        } else if (c < 128){
          v = remb[rid[n]*64 + (c-64)];
        } else {
          int i = c - 128;
          float rate = exp2f(-(float)(2*(i>>1)) * (1.0f/64.0f) * 13.287712379549449f);
          float s, cc;
          sincosf((float)n * rate, &s, &cc);
          v = (i & 1) ? cc : s;
        }
      }
      feats[(size_t)n*192 + c] = f2bf(v);
    }
  } else if (b < 13728){
    int idx = (b - 12512)*256 + threadIdx.x;
    if (idx < 49152){               // inproj: [192][256] -> [256][192]
      int n = idx / 192, k = idx - n*192;
      wtin[idx] = f2bf(ipw[k*256 + n]);
    } else {
      int j = idx - 49152;          // gat: 4 x [256][256]^T
      if (j < 262144){
        int l = j >> 16, rem = j & 65535;
        int n = rem >> 8, k = rem & 255;
        wtl[j] = f2bf(gatw[l*65536 + k*256 + n]);
      }
    }
  } else if (b < 13792){
    // vmat[l][16][256]: rows 0..3 = W^T·a_src, 4..7 = W^T·a_dst, 8..15 zero
    int idx = (b - 13728)*256 + threadIdx.x;
    if (idx < 16384){
      int l = idx >> 12, rem = idx & 4095, v = rem >> 8, k = rem & 255;
      float s = 0.f;
      if (v < 8){
        const float* a = (v < 4) ? (asrc + l*256 + v*64) : (adst + l*256 + (v-4)*64);
        const float* w = gatw + (size_t)l*65536 + k*256 + (v & 3)*64;
        #pragma unroll 8
        for (int c=0;c<64;++c) s += w[c]*a[c];
      }
      vmat[idx] = f2bf(s);
    }
  } else {
    int i = (b - 13792)*256 + threadIdx.x;
    if (i < ET){
      int d = (i < EE) ? ei[EE + i] : (i - EE);
      atomicAdd(&deg[d], 1);
    }
  }
}

// ---------------- scan1: per-block exclusive scan + block totals ----------------
__global__ void k_scan1(const int* __restrict__ deg, int* __restrict__ row_off, int* __restrict__ part){
  __shared__ int s[256];
  int n = blockIdx.x*256 + threadIdx.x;
  int v = (n < NN) ? deg[n] : 0;
  s[threadIdx.x] = v;
  __syncthreads();
  for (int off=1; off<256; off<<=1){
    int t = (threadIdx.x >= off) ? s[threadIdx.x - off] : 0;
    __syncthreads();
    s[threadIdx.x] += t;
    __syncthreads();
  }
  if (n < NN) row_off[n] = s[threadIdx.x] - v;
  if (threadIdx.x == 255) part[blockIdx.x] = s[255];
}

// ---------------- scan23 ----------------
__global__ void k_scan23(int* __restrict__ row_off, const int* __restrict__ part, int nparts){
  __shared__ int sp[256];
  int t = threadIdx.x;
  sp[t] = (t < nparts && t < (int)blockIdx.x) ? part[t] : 0;
  __syncthreads();
  for (int off=128; off; off>>=1){
    if (t < off) sp[t] += sp[t+off];
    __syncthreads();
  }
  int n = blockIdx.x*256 + t;
  if (n < NN) row_off[n] += sp[0];
}

__global__ void k_scatter(const int* __restrict__ ei, const int* __restrict__ row_off,
                          int* __restrict__ cur, int* __restrict__ csr_src){
  int i = blockIdx.x*blockDim.x + threadIdx.x;
  if (i >= ET) return;
  int s, d;
  if (i < EE){ s = ei[i]; d = ei[EE + i]; } else { s = i - EE; d = i - EE; }
  int pos = row_off[d] + atomicAdd(&cur[d], 1);
  csr_src[pos] = s;
}

// ================ m97-style MFMA GEMM, double-buffered K-loop ================
// C[M][256](bf16) = A[M][K](bf16) @ Wt[256][K]^T (+bias).  grid (391, 2).
// Per K-step: A 128x32 + B 128x32 in LDS via global_load_lds; stage(k+1) issued
// before compute(k); ONE barrier per step. Swizzle c = p ^ ((r>>2)&3): bank-starts
// cover all 8 groups (2-way aliasing = free), DMA source stays 64B-segment coalesced.
template<int K>
__global__ __launch_bounds__(256, 3) void k_gemm(
    const u16* __restrict__ A, const u16* __restrict__ Wt,
    const float* __restrict__ bias, const u16* __restrict__ vmat,
    float* __restrict__ ss, float* __restrict__ sd,
    u16* __restrict__ C, int M)
{
  __shared__ u16 Asl[2][128*32];   // 8 KB x2
  __shared__ u16 Bsl[2][128*32];   // 8 KB x2
  int tid = threadIdx.x;
  int wave = tid >> 6, lane = tid & 63, quad = lane >> 4, lm = lane & 15;
  int r0 = blockIdx.x * 128;
  int cb = blockIdx.y;                   // col half of C (0/1)
  int rW = (wave >> 1) * 64;
  int cW = (wave & 1) * 64;
  bool doScore = vmat && (cb == 0) && ((wave & 1) == 0);

  f32x4 acc[4][4] = {};
  f32x4 accs[4] = {};

  auto stage = [&](int buf, int k0){
    for (int m = wave; m < 8; m += 4){
      int s = m*64 + lane;
      int r = s >> 2, p = s & 3;
      int c = p ^ ((r >> 2) & 3);
      dma16(A + (size_t)(r0 + r)*K + k0 + c*8, &Asl[buf][m*512]);
    }
    for (int m = wave; m < 8; m += 4){
      int s = m*64 + lane;
      int r = s >> 2, p = s & 3;
      int c = p ^ ((r >> 2) & 3);
      dma16(Wt + (size_t)(cb*128 + r)*K + k0 + c*8, &Bsl[buf][m*512]);
    }
  };

  stage(0, 0);
  __syncthreads();

  for (int ks = 0; ks < K/32; ++ks){
    int cur = ks & 1;
    if (ks + 1 < K/32) stage(cur ^ 1, (ks+1)*32);

    bf16x8 a[4], b[4];
    #pragma unroll
    for (int i=0;i<4;++i){
      int row = rW + i*16 + lm;
      int slot = row*4 + (quad ^ ((row >> 2) & 3));
      a[i] = *(const bf16x8*)(&Asl[cur][slot*8]);
    }
    #pragma unroll
    for (int j=0;j<4;++j){
      int row = cW + j*16 + lm;
      int slot = row*4 + (quad ^ ((row >> 2) & 3));
      b[j] = *(const bf16x8*)(&Bsl[cur][slot*8]);
    }
    #pragma unroll
    for (int i=0;i<4;++i)
      #pragma unroll
      for (int j=0;j<4;++j)
        acc[i][j] = __builtin_amdgcn_mfma_f32_16x16x32_bf16(a[i], b[j], acc[i][j], 0, 0, 0);
    if (doScore){
      bf16x8 bs = *(const bf16x8*)(vmat + (size_t)lm*K + ks*32 + quad*8);
      #pragma unroll
      for (int i=0;i<4;++i)
        accs[i] = __builtin_amdgcn_mfma_f32_16x16x32_bf16(a[i], bs, accs[i], 0, 0, 0);
    }
    __syncthreads();   // drains next-step dma; protects cur buf before restage
  }

  // scores: C/D layout col=lane&15, row=quad*4+reg  [verified m89/m91]
  if (doScore){
    #pragma unroll
    for (int i=0;i<4;++i){
      #pragma unroll
      for (int r=0;r<4;++r){
        int row = r0 + rW + i*16 + quad*4 + r;
        if (row < M){
          if (lm < 4)      ss[row*4 + lm]     = accs[i][r];
          else if (lm < 8) sd[row*4 + lm - 4] = accs[i][r];
        }
      }
    }
  }

  // epilogue: direct stores
  #pragma unroll
  for (int i=0;i<4;++i){
    #pragma unroll
    for (int r=0;r<4;++r){
      int row = r0 + rW + i*16 + quad*4 + r;
      if (row < M){
        #pragma unroll
        for (int j=0;j<4;++j){
          int col = cb*128 + cW + j*16 + lm;
          float v = acc[i][j][r];
          if (bias) v += bias[col];
          C[(size_t)row*256 + col] = f2bf(v);
        }
      }
    }
  }
}

// ================ aggregate core (dual-chain, R6-best form) ================
// returns 8 LN'd output floats for node n, channels c0..c0+7 (hl = lane&31)
__device__ __forceinline__ void agg_core(
    int n, int hl,
    const u16* __restrict__ h2, const float* __restrict__ ssrc, const float* __restrict__ sdst,
    const int* __restrict__ row_off, const int* __restrict__ deg, const int* __restrict__ csr_src,
    const float* __restrict__ bias, const float* __restrict__ g, const float* __restrict__ bb,
    float out[8])
{
  int c0 = hl*8;
  int head = hl >> 3;
  float sdh = sdst[n*4 + head];
  int ro = row_off[n];
  int dg = deg[n];
  float denA = 0.f, denB = 0.f;
  float a0=0,a1=0,a2=0,a3=0,a4=0,a5=0,a6=0,a7=0;
  float b0=0,b1=0,b2=0,b3=0,b4=0,b5=0,b6=0,b7=0;
  int j = 0;
  for (; j + 2 <= dg; j += 2){
    int sA = csr_src[ro+j];
    int sB = csr_src[ro+j+1];
    uint4 uA = *(const uint4*)(h2 + (size_t)sA*HIDD + c0);
    uint4 uB = *(const uint4*)(h2 + (size_t)sB*HIDD + c0);
    float eA = ssrc[sA*4+head] + sdh;
    float eB = ssrc[sB*4+head] + sdh;
    eA = (eA > 0.f) ? eA : 0.2f*eA;
    eB = (eB > 0.f) ? eB : 0.2f*eB;
    float xA = __expf(eA), xB = __expf(eB);
    denA += xA; denB += xB;
    a0 += xA*bflo(uA.x); a1 += xA*bfhi(uA.x);
    a2 += xA*bflo(uA.y); a3 += xA*bfhi(uA.y);
    a4 += xA*bflo(uA.z); a5 += xA*bfhi(uA.z);
    a6 += xA*bflo(uA.w); a7 += xA*bfhi(uA.w);
    b0 += xB*bflo(uB.x); b1 += xB*bfhi(uB.x);
    b2 += xB*bflo(uB.y); b3 += xB*bfhi(uB.y);
    b4 += xB*bflo(uB.z); b5 += xB*bfhi(uB.z);
    b6 += xB*bflo(uB.w); b7 += xB*bfhi(uB.w);
  }
  if (j < dg){
    int sA = csr_src[ro+j];
    uint4 uA = *(const uint4*)(h2 + (size_t)sA*HIDD + c0);
    float eA = ssrc[sA*4+head] + sdh;
    eA = (eA > 0.f) ? eA : 0.2f*eA;
    float xA = __expf(eA);
    denA += xA;
    a0 += xA*bflo(uA.x); a1 += xA*bfhi(uA.x);
    a2 += xA*bflo(uA.y); a3 += xA*bfhi(uA.y);
    a4 += xA*bflo(uA.z); a5 += xA*bfhi(uA.z);
    a6 += xA*bflo(uA.w); a7 += xA*bfhi(uA.w);
  }
  float inv = 1.f / (denA + denB);
  float y[8];
  y[0]=a0+b0; y[1]=a1+b1; y[2]=a2+b2; y[3]=a3+b3;
  y[4]=a4+b4; y[5]=a5+b5; y[6]=a6+b6; y[7]=a7+b7;
  float4 bi0 = *(const float4*)(bias + c0);
  float4 bi1 = *(const float4*)(bias + c0 + 4);
  y[0]=fmaxf(y[0]*inv+bi0.x,0.f); y[1]=fmaxf(y[1]*inv+bi0.y,0.f);
  y[2]=fmaxf(y[2]*inv+bi0.z,0.f); y[3]=fmaxf(y[3]*inv+bi0.w,0.f);
  y[4]=fmaxf(y[4]*inv+bi1.x,0.f); y[5]=fmaxf(y[5]*inv+bi1.y,0.f);
  y[6]=fmaxf(y[6]*inv+bi1.z,0.f); y[7]=fmaxf(y[7]*inv+bi1.w,0.f);
  float sum = (y[0]+y[1])+(y[2]+y[3])+((y[4]+y[5])+(y[6]+y[7]));
  #pragma unroll
  for (int o=16;o>=1;o>>=1) sum += __shfl_xor(sum, o);
  float mu = sum * (1.f/256.f);
  float d[8], sq = 0.f;
  #pragma unroll
  for (int k=0;k<8;++k){ d[k] = y[k]-mu; sq += d[k]*d[k]; }
  #pragma unroll
  for (int o=16;o>=1;o>>=1) sq += __shfl_xor(sq, o);
  float rs = rsqrtf(sq*(1.f/256.f) + LN_EPSF);
  float4 g0 = *(const float4*)(g + c0);
  float4 g1 = *(const float4*)(g + c0 + 4);
  float4 q0 = *(const float4*)(bb + c0);
  float4 q1 = *(const float4*)(bb + c0 + 4);
  out[0]=d[0]*rs*g0.x+q0.x; out[1]=d[1]*rs*g0.y+q0.y;
  out[2]=d[2]*rs*g0.z+q0.z; out[3]=d[3]*rs*g0.w+q0.w;
  out[4]=d[4]*rs*g1.x+q1.x; out[5]=d[5]*rs*g1.y+q1.y;
  out[6]=d[6]*rs*g1.z+q1.z; out[7]=d[7]*rs*g1.w+q1.w;
}

// ---------------- aggregate -> hout (layers 0..2) ----------------
__global__ __launch_bounds__(256) void k_aggregate(
    const u16* __restrict__ h2, const float* __restrict__ ssrc, const float* __restrict__ sdst,
    const int* __restrict__ row_off, const int* __restrict__ deg, const int* __restrict__ csr_src,
    const float* __restrict__ bias, const float* __restrict__ g, const float* __restrict__ bb,
    u16* __restrict__ hout)
{
  int wv = (blockIdx.x*blockDim.x + threadIdx.x) >> 6;
  int lane = threadIdx.x & 63;
  int half = lane >> 5, hl = lane & 31;
  int n = wv*2 + half;
  if (n >= NN) return;
  float out[8];
  agg_core(n, hl, h2, ssrc, sdst, row_off, deg, csr_src, bias, g, bb, out);
  uint4 o4;
  o4.x = pack2(out[0], out[1]);
  o4.y = pack2(out[2], out[3]);
  o4.z = pack2(out[4], out[5]);
  o4.w = pack2(out[6], out[7]);
  *(uint4*)(hout + (size_t)n*HIDD + hl*8) = o4;
}

// ---------------- final aggregate fused with mean-pool accumulation ----------------
__global__ __launch_bounds__(256) void k_aggpool(
    const u16* __restrict__ h2, const float* __restrict__ ssrc, const float* __restrict__ sdst,
    const int* __restrict__ row_off, const int* __restrict__ deg, const int* __restrict__ csr_src,
    const float* __restrict__ bias, const float* __restrict__ g, const float* __restrict__ bb,
    const int* __restrict__ batch, float* __restrict__ pooled, float* __restrict__ cnt)
{
  __shared__ float pacc[256];
  int tid = threadIdx.x;
  int nb0 = blockIdx.x*8;
  int wv = tid >> 6, lane = tid & 63, half = lane >> 5, hl = lane & 31;
  int n = nb0 + wv*2 + half;
  int nlast = min(nb0+7, NN-1);
  bool uni = (batch[nb0] == batch[nlast]);   // batch sorted
  if (uni) pacc[tid] = 0.f;
  __syncthreads();
  bool valid = (n < NN);
  float out[8];
  if (valid)
    agg_core(n, hl, h2, ssrc, sdst, row_off, deg, csr_src, bias, g, bb, out);
  if (uni){
    if (valid){
      #pragma unroll
      for (int k=0;k<8;++k) atomicAdd(&pacc[hl*8+k], out[k]);
    }
    __syncthreads();
    int b = batch[nb0];
    atomicAdd(&pooled[b*256 + tid], pacc[tid]);
    if (tid == 0) atomicAdd(&cnt[b], (float)(min(NN - nb0, 8)));
  } else {
    if (valid){
      int b = batch[n];
      #pragma unroll
      for (int k=0;k<8;++k) atomicAdd(&pooled[b*256 + hl*8 + k], out[k]);
      if (hl == 0) atomicAdd(&cnt[b], 1.0f);
    }
  }
}

// ---------------- readout: gelu(pooled@W1+b1)@W2+b2 (fp32, tiny) ----------------
__global__ __launch_bounds__(256) void k_readout(
    const float* __restrict__ pooled, const float* __restrict__ cnt,
    const float* __restrict__ w1, const float* __restrict__ b1,
    const float* __restrict__ w2, const float* __restrict__ b2,
    float* __restrict__ out)
{
  __shared__ float p[256], mid[256];
  int b = blockIdx.x, t = threadIdx.x;
  float c = fmaxf(cnt[b], 1.f);
  p[t] = pooled[b*HIDD + t] / c;
  __syncthreads();
  float acc = b1[t];
  for (int k=0;k<256;++k) acc += p[k]*w1[k*256+t];
  mid[t] = 0.5f*acc*(1.f + erff(acc*0.70710678118654752f));
  __syncthreads();
  float acc2 = b2[t];
  for (int k=0;k<256;++k) acc2 += mid[k]*w2[k*256+t];
  out[b*HIDD + t] = acc2;
}

extern "C" void kernel_launch(void* const* d_in, const int* in_sizes, int n_in,
                              void* d_out, int out_size, void* d_ws, size_t ws_size,
                              hipStream_t stream)
{
  const float* x    = (const float*)d_in[0];
  const float* remb = (const float*)d_in[1];
  const float* ipw  = (const float*)d_in[2];
  const float* ipb  = (const float*)d_in[3];
  const float* gatw = (const float*)d_in[4];
  const float* asrc = (const float*)d_in[5];
  const float* adst = (const float*)d_in[6];
  const float* gatb = (const float*)d_in[7];
  const float* lng  = (const float*)d_in[8];
  const float* lnb  = (const float*)d_in[9];
  const float* row1 = (const float*)d_in[10];
  const float* rob1 = (const float*)d_in[11];
  const float* row2 = (const float*)d_in[12];
  const float* rob2 = (const float*)d_in[13];
  const int* ei   = (const int*)d_in[14];
  const int* batch= (const int*)d_in[15];
  const int* rid  = (const int*)d_in[16];

  char* ws = (char*)d_ws;
  int*   deg  = (int*)  (ws + 0);          // 200192
  int*   cur  = (int*)  (ws + 200192);     // 200192
  float* cnt  = (float*)(ws + 400384);     // 256
  float* pool = (float*)(ws + 400640);     // 16384
  // ZERO_BYTES = 417024
  int*   row  = (int*)  (ws + 417024);     // 200192
  int*   part = (int*)  (ws + 617216);     // 1024
  int*   csr  = (int*)  (ws + 618240);     // 1800192 -> 2418432
  float* ss   = (float*)(ws + 2418432);    // 800768
  float* sd   = (float*)(ws + 3219200);    // 800768  -> 4019968
  u16*   vmat = (u16*)  (ws + 4019968);    // 32768   -> 4052736
  u16*   feats= (u16*)  (ws + 4052736);    // 19218432-> 23271168
  u16*   wtin = (u16*)  (ws + 23271168);   // 98304   -> 23369472
  u16*   wtl  = (u16*)  (ws + 23369472);   // 524288  -> 23893760
  u16*   hA   = (u16*)  (ws + 23893760);   // 25624576-> 49518336
  u16*   hB   = (u16*)  (ws + 49518336);   // 25624576-> 75142912

  hipMemsetAsync(ws, 0, 417024, stream);

  k_setup <<<15550, 256, 0, stream>>>(x, remb, rid, feats, ipw, gatw, wtin, wtl,
                                      asrc, adst, vmat, ei, deg);
  k_scan1 <<<196, 256, 0, stream>>>(deg, row, part);
  k_scan23<<<196, 256, 0, stream>>>(row, part, 196);
  k_scatter<<<1758, 256, 0, stream>>>(ei, row, cur, csr);

  // input projection (bias, no scores): feats -> hA ; K=192
  k_gemm<KIN><<<dim3(391,2), 256, 0, stream>>>(feats, wtin, ipb, nullptr,
                                               nullptr, nullptr, hA, NN);

  for (int l = 0; l < 4; ++l){
    // layer GEMM: hA -> hB, MFMA-fused scores via vmat[l]; K=256
    k_gemm<HIDD><<<dim3(391,2), 256, 0, stream>>>(hA, wtl + (size_t)l*HIDD*HIDD, nullptr,
                                                  vmat + (size_t)l*16*256, ss, sd, hB, NN);
    if (l < 3){
      k_aggregate<<<6250, 256, 0, stream>>>(hB, ss, sd, row, deg, csr,
                                            gatb + l*HIDD, lng + l*HIDD, lnb + l*HIDD, hA);
    } else {
      k_aggpool<<<6250, 256, 0, stream>>>(hB, ss, sd, row, deg, csr,
                                          gatb + l*HIDD, lng + l*HIDD, lnb + l*HIDD,
                                          batch, pool, cnt);
    }
  }

  k_readout<<<16, 256, 0, stream>>>(pool, cnt, row1, rob1, row2, rob2, (float*)d_out);
}

// Round 13
// 490.022 us; speedup vs baseline: 1.0856x; 1.0856x over previous
//
#include <hip/hip_runtime.h>
#include <cmath>

typedef unsigned short u16;
typedef unsigned int u32;
typedef short bf16x8 __attribute__((ext_vector_type(8)));
typedef float f32x4 __attribute__((ext_vector_type(4)));

#define NN 50000      // nodes
#define MP 50048      // padded to 128*391
#define EE 400000     // raw edges
#define ET 450000     // edges + self loops
#define HIDD 256
#define KIN 192       // 3*F
#define LN_EPSF 1e-5f

__device__ __forceinline__ float bf2f(u16 u){ return __uint_as_float(((u32)u)<<16); }
__device__ __forceinline__ u16 f2bf(float f){
  u32 x = __float_as_uint(f);
  u32 r = x + 0x7fffu + ((x>>16)&1u);   // RNE
  return (u16)(r>>16);
}
__device__ __forceinline__ float bflo(u32 v){ return __uint_as_float(v<<16); }
__device__ __forceinline__ float bfhi(u32 v){ return __uint_as_float(v & 0xffff0000u); }
__device__ __forceinline__ u32 pack2(float a, float b){ return (u32)f2bf(a) | ((u32)f2bf(b)<<16); }

__device__ __forceinline__ void dma16(const u16* g, u16* lds){
  __builtin_amdgcn_global_load_lds(
      (const __attribute__((address_space(1))) void*)g,
      (__attribute__((address_space(3))) void*)lds, 16, 0, 0);
}

// ================ merged setup: feats | wt | vmat | degree (partitioned by block) ================
__global__ __launch_bounds__(256) void k_setup(
    const float* __restrict__ x, const float* __restrict__ remb, const int* __restrict__ rid,
    u16* __restrict__ feats,
    const float* __restrict__ ipw, const float* __restrict__ gatw,
    u16* __restrict__ wtin, u16* __restrict__ wtl,
    const float* __restrict__ asrc, const float* __restrict__ adst, u16* __restrict__ vmat,
    const int* __restrict__ ei, int* __restrict__ deg)
{
  int b = blockIdx.x;
  if (b < 12512){
    int e = b*768 + threadIdx.x;
    #pragma unroll
    for (int it=0; it<3; ++it, e+=256){
      int n = e / 192;
      int c = e - n*192;
      if (n >= MP) break;
      float v = 0.f;
      if (n < NN){
        if (c < 64){
          v = x[n*64 + c];
        } else if (c < 128){
          v = remb[rid[n]*64 + (c-64)];
        } else {
          int i = c - 128;
          float rate = exp2f(-(float)(2*(i>>1)) * (1.0f/64.0f) * 13.287712379549449f);
          float s, cc;
          sincosf((float)n * rate, &s, &cc);
          v = (i & 1) ? cc : s;
        }
      }
      feats[(size_t)n*192 + c] = f2bf(v);
    }
  } else if (b < 13728){
    int idx = (b - 12512)*256 + threadIdx.x;
    if (idx < 49152){               // inproj: [192][256] -> [256][192]
      int n = idx / 192, k = idx - n*192;
      wtin[idx] = f2bf(ipw[k*256 + n]);
    } else {
      int j = idx - 49152;          // gat: 4 x [256][256]^T
      if (j < 262144){
        int l = j >> 16, rem = j & 65535;
        int n = rem >> 8, k = rem & 255;
        wtl[j] = f2bf(gatw[l*65536 + k*256 + n]);
      }
    }
  } else if (b < 13792){
    // vmat[l][16][256]: rows 0..3 = W^T·a_src, 4..7 = W^T·a_dst, 8..15 zero
    int idx = (b - 13728)*256 + threadIdx.x;
    if (idx < 16384){
      int l = idx >> 12, rem = idx & 4095, v = rem >> 8, k = rem & 255;
      float s = 0.f;
      if (v < 8){
        const float* a = (v < 4) ? (asrc + l*256 + v*64) : (adst + l*256 + (v-4)*64);
        const float* w = gatw + (size_t)l*65536 + k*256 + (v & 3)*64;
        #pragma unroll 8
        for (int c=0;c<64;++c) s += w[c]*a[c];
      }
      vmat[idx] = f2bf(s);
    }
  } else {
    int i = (b - 13792)*256 + threadIdx.x;
    if (i < ET){
      int d = (i < EE) ? ei[EE + i] : (i - EE);
      atomicAdd(&deg[d], 1);
    }
  }
}

// ---------------- scan1: per-block exclusive scan + block totals ----------------
__global__ void k_scan1(const int* __restrict__ deg, int* __restrict__ row_off, int* __restrict__ part){
  __shared__ int s[256];
  int n = blockIdx.x*256 + threadIdx.x;
  int v = (n < NN) ? deg[n] : 0;
  s[threadIdx.x] = v;
  __syncthreads();
  for (int off=1; off<256; off<<=1){
    int t = (threadIdx.x >= off) ? s[threadIdx.x - off] : 0;
    __syncthreads();
    s[threadIdx.x] += t;
    __syncthreads();
  }
  if (n < NN) row_off[n] = s[threadIdx.x] - v;
  if (threadIdx.x == 255) part[blockIdx.x] = s[255];
}

// ---------------- scan23 ----------------
__global__ void k_scan23(int* __restrict__ row_off, const int* __restrict__ part, int nparts){
  __shared__ int sp[256];
  int t = threadIdx.x;
  sp[t] = (t < nparts && t < (int)blockIdx.x) ? part[t] : 0;
  __syncthreads();
  for (int off=128; off; off>>=1){
    if (t < off) sp[t] += sp[t+off];
    __syncthreads();
  }
  int n = blockIdx.x*256 + t;
  if (n < NN) row_off[n] += sp[0];
}

__global__ void k_scatter(const int* __restrict__ ei, const int* __restrict__ row_off,
                          int* __restrict__ cur, int* __restrict__ csr_src){
  int i = blockIdx.x*blockDim.x + threadIdx.x;
  if (i >= ET) return;
  int s, d;
  if (i < EE){ s = ei[i]; d = ei[EE + i]; } else { s = i - EE; d = i - EE; }
  int pos = row_off[d] + atomicAdd(&cur[d], 1);
  csr_src[pos] = s;
}

// ================ m97-style MFMA GEMM, double-buffered K-loop ================
// C[M][256](bf16) = A[M][K](bf16) @ Wt[256][K]^T (+bias).  grid (391, 2).
// Per K-step: A 128x32 + B 128x32 in LDS via global_load_lds; stage(k+1) issued
// before compute(k); ONE barrier per step. Swizzle c = p ^ ((r>>2)&3): bank-starts
// cover all 8 groups (2-way aliasing = free), DMA source stays 64B-segment coalesced.
template<int K>
__global__ __launch_bounds__(256, 3) void k_gemm(
    const u16* __restrict__ A, const u16* __restrict__ Wt,
    const float* __restrict__ bias, const u16* __restrict__ vmat,
    float* __restrict__ ss, float* __restrict__ sd,
    u16* __restrict__ C, int M)
{
  __shared__ u16 Asl[2][128*32];   // 8 KB x2
  __shared__ u16 Bsl[2][128*32];   // 8 KB x2
  int tid = threadIdx.x;
  int wave = tid >> 6, lane = tid & 63, quad = lane >> 4, lm = lane & 15;
  int r0 = blockIdx.x * 128;
  int cb = blockIdx.y;                   // col half of C (0/1)
  int rW = (wave >> 1) * 64;
  int cW = (wave & 1) * 64;
  bool doScore = vmat && (cb == 0) && ((wave & 1) == 0);

  f32x4 acc[4][4] = {};
  f32x4 accs[4] = {};

  auto stage = [&](int buf, int k0){
    for (int m = wave; m < 8; m += 4){
      int s = m*64 + lane;
      int r = s >> 2, p = s & 3;
      int c = p ^ ((r >> 2) & 3);
      dma16(A + (size_t)(r0 + r)*K + k0 + c*8, &Asl[buf][m*512]);
    }
    for (int m = wave; m < 8; m += 4){
      int s = m*64 + lane;
      int r = s >> 2, p = s & 3;
      int c = p ^ ((r >> 2) & 3);
      dma16(Wt + (size_t)(cb*128 + r)*K + k0 + c*8, &Bsl[buf][m*512]);
    }
  };

  stage(0, 0);
  __syncthreads();

  for (int ks = 0; ks < K/32; ++ks){
    int cur = ks & 1;
    if (ks + 1 < K/32) stage(cur ^ 1, (ks+1)*32);

    bf16x8 a[4], b[4];
    #pragma unroll
    for (int i=0;i<4;++i){
      int row = rW + i*16 + lm;
      int slot = row*4 + (quad ^ ((row >> 2) & 3));
      a[i] = *(const bf16x8*)(&Asl[cur][slot*8]);
    }
    #pragma unroll
    for (int j=0;j<4;++j){
      int row = cW + j*16 + lm;
      int slot = row*4 + (quad ^ ((row >> 2) & 3));
      b[j] = *(const bf16x8*)(&Bsl[cur][slot*8]);
    }
    #pragma unroll
    for (int i=0;i<4;++i)
      #pragma unroll
      for (int j=0;j<4;++j)
        acc[i][j] = __builtin_amdgcn_mfma_f32_16x16x32_bf16(a[i], b[j], acc[i][j], 0, 0, 0);
    if (doScore){
      bf16x8 bs = *(const bf16x8*)(vmat + (size_t)lm*K + ks*32 + quad*8);
      #pragma unroll
      for (int i=0;i<4;++i)
        accs[i] = __builtin_amdgcn_mfma_f32_16x16x32_bf16(a[i], bs, accs[i], 0, 0, 0);
    }
    __syncthreads();   // drains next-step dma; protects cur buf before restage
  }

  // scores: C/D layout col=lane&15, row=quad*4+reg  [verified m89/m91]
  if (doScore){
    #pragma unroll
    for (int i=0;i<4;++i){
      #pragma unroll
      for (int r=0;r<4;++r){
        int row = r0 + rW + i*16 + quad*4 + r;
        if (row < M){
          if (lm < 4)      ss[row*4 + lm]     = accs[i][r];
          else if (lm < 8) sd[row*4 + lm - 4] = accs[i][r];
        }
      }
    }
  }

  // epilogue: direct stores
  #pragma unroll
  for (int i=0;i<4;++i){
    #pragma unroll
    for (int r=0;r<4;++r){
      int row = r0 + rW + i*16 + quad*4 + r;
      if (row < M){
        #pragma unroll
        for (int j=0;j<4;++j){
          int col = cb*128 + cW + j*16 + lm;
          float v = acc[i][j][r];
          if (bias) v += bias[col];
          C[(size_t)row*256 + col] = f2bf(v);
        }
      }
    }
  }
}

// ---------------- fused GAT aggregate + bias + relu + layernorm ----------------
// 2 nodes per wave (32 lanes x 8 ch), dual-chain (R6 best form: 43.3us memory-floor)
__global__ __launch_bounds__(256) void k_aggregate(
    const u16* __restrict__ h2, const float* __restrict__ ssrc, const float* __restrict__ sdst,
    const int* __restrict__ row_off, const int* __restrict__ deg, const int* __restrict__ csr_src,
    const float* __restrict__ bias, const float* __restrict__ g, const float* __restrict__ bb,
    u16* __restrict__ hout)
{
  int wv = (blockIdx.x*blockDim.x + threadIdx.x) >> 6;
  int lane = threadIdx.x & 63;
  int half = lane >> 5;
  int hl = lane & 31;
  int n = wv*2 + half;
  if (n >= NN) return;
  int c0 = hl*8;
  int head = hl >> 3;
  float sdh = sdst[n*4 + head];
  int ro = row_off[n];
  int dg = deg[n];
  float denA = 0.f, denB = 0.f;
  float a0=0,a1=0,a2=0,a3=0,a4=0,a5=0,a6=0,a7=0;
  float b0=0,b1=0,b2=0,b3=0,b4=0,b5=0,b6=0,b7=0;
  int j = 0;
  for (; j + 2 <= dg; j += 2){
    int sA = csr_src[ro+j];
    int sB = csr_src[ro+j+1];
    uint4 uA = *(const uint4*)(h2 + (size_t)sA*HIDD + c0);
    uint4 uB = *(const uint4*)(h2 + (size_t)sB*HIDD + c0);
    float eA = ssrc[sA*4+head] + sdh;
    float eB = ssrc[sB*4+head] + sdh;
    eA = (eA > 0.f) ? eA : 0.2f*eA;
    eB = (eB > 0.f) ? eB : 0.2f*eB;
    float xA = __expf(eA), xB = __expf(eB);
    denA += xA; denB += xB;
    a0 += xA*bflo(uA.x); a1 += xA*bfhi(uA.x);
    a2 += xA*bflo(uA.y); a3 += xA*bfhi(uA.y);
    a4 += xA*bflo(uA.z); a5 += xA*bfhi(uA.z);
    a6 += xA*bflo(uA.w); a7 += xA*bfhi(uA.w);
    b0 += xB*bflo(uB.x); b1 += xB*bfhi(uB.x);
    b2 += xB*bflo(uB.y); b3 += xB*bfhi(uB.y);
    b4 += xB*bflo(uB.z); b5 += xB*bfhi(uB.z);
    b6 += xB*bflo(uB.w); b7 += xB*bfhi(uB.w);
  }
  if (j < dg){
    int sA = csr_src[ro+j];
    uint4 uA = *(const uint4*)(h2 + (size_t)sA*HIDD + c0);
    float eA = ssrc[sA*4+head] + sdh;
    eA = (eA > 0.f) ? eA : 0.2f*eA;
    float xA = __expf(eA);
    denA += xA;
    a0 += xA*bflo(uA.x); a1 += xA*bfhi(uA.x);
    a2 += xA*bflo(uA.y); a3 += xA*bfhi(uA.y);
    a4 += xA*bflo(uA.z); a5 += xA*bfhi(uA.z);
    a6 += xA*bflo(uA.w); a7 += xA*bfhi(uA.w);
  }
  float inv = 1.f / (denA + denB);
  float y[8];
  y[0]=a0+b0; y[1]=a1+b1; y[2]=a2+b2; y[3]=a3+b3;
  y[4]=a4+b4; y[5]=a5+b5; y[6]=a6+b6; y[7]=a7+b7;
  float4 bi0 = *(const float4*)(bias + c0);
  float4 bi1 = *(const float4*)(bias + c0 + 4);
  y[0]=fmaxf(y[0]*inv+bi0.x,0.f); y[1]=fmaxf(y[1]*inv+bi0.y,0.f);
  y[2]=fmaxf(y[2]*inv+bi0.z,0.f); y[3]=fmaxf(y[3]*inv+bi0.w,0.f);
  y[4]=fmaxf(y[4]*inv+bi1.x,0.f); y[5]=fmaxf(y[5]*inv+bi1.y,0.f);
  y[6]=fmaxf(y[6]*inv+bi1.z,0.f); y[7]=fmaxf(y[7]*inv+bi1.w,0.f);
  // layernorm over 256 channels within the 32-lane half (xor-closed, offsets 1..16)
  float sum = (y[0]+y[1])+(y[2]+y[3])+((y[4]+y[5])+(y[6]+y[7]));
  #pragma unroll
  for (int o=16;o>=1;o>>=1) sum += __shfl_xor(sum, o);
  float mu = sum * (1.f/256.f);
  float d[8], sq = 0.f;
  #pragma unroll
  for (int k=0;k<8;++k){ d[k] = y[k]-mu; sq += d[k]*d[k]; }
  #pragma unroll
  for (int o=16;o>=1;o>>=1) sq += __shfl_xor(sq, o);
  float rs = rsqrtf(sq*(1.f/256.f) + LN_EPSF);
  float4 g0 = *(const float4*)(g + c0);
  float4 g1 = *(const float4*)(g + c0 + 4);
  float4 q0 = *(const float4*)(bb + c0);
  float4 q1 = *(const float4*)(bb + c0 + 4);
  uint4 o4;
  o4.x = pack2(d[0]*rs*g0.x + q0.x, d[1]*rs*g0.y + q0.y);
  o4.y = pack2(d[2]*rs*g0.z + q0.z, d[3]*rs*g0.w + q0.w);
  o4.z = pack2(d[4]*rs*g1.x + q1.x, d[5]*rs*g1.y + q1.y);
  o4.w = pack2(d[6]*rs*g1.z + q1.z, d[7]*rs*g1.w + q1.w);
  *(uint4*)(hout + (size_t)n*HIDD + c0) = o4;
}

// ---------------- global mean pool: 2000 blocks, run-length atomics (batch sorted) ----------------
__global__ __launch_bounds__(256) void k_pool(
    const u16* __restrict__ h, const int* __restrict__ batch,
    float* __restrict__ pooled, float* __restrict__ cnt)
{
  const int chunk = 25;  // 2000*25 >= NN
  int t = threadIdx.x;
  int n0 = blockIdx.x*chunk;
  int n1 = min(n0 + chunk, NN);
  if (n0 >= n1) return;
  float acc = 0.f;
  int curb = batch[n0];
  int runStart = n0;
  for (int n=n0; n<n1; ++n){
    int b = batch[n];
    if (b != curb){
      atomicAdd(&pooled[curb*HIDD + t], acc);
      if (t == 0) atomicAdd(&cnt[curb], (float)(n - runStart));
      acc = 0.f; curb = b; runStart = n;
    }
    acc += bf2f(h[(size_t)n*HIDD + t]);
  }
  atomicAdd(&pooled[curb*HIDD + t], acc);
  if (t == 0) atomicAdd(&cnt[curb], (float)(n1 - runStart));
}

// ---------------- readout: gelu(pooled@W1+b1)@W2+b2 (fp32, tiny) ----------------
__global__ __launch_bounds__(256) void k_readout(
    const float* __restrict__ pooled, const float* __restrict__ cnt,
    const float* __restrict__ w1, const float* __restrict__ b1,
    const float* __restrict__ w2, const float* __restrict__ b2,
    float* __restrict__ out)
{
  __shared__ float p[256], mid[256];
  int b = blockIdx.x, t = threadIdx.x;
  float c = fmaxf(cnt[b], 1.f);
  p[t] = pooled[b*HIDD + t] / c;
  __syncthreads();
  float acc = b1[t];
  for (int k=0;k<256;++k) acc += p[k]*w1[k*256+t];
  mid[t] = 0.5f*acc*(1.f + erff(acc*0.70710678118654752f));
  __syncthreads();
  float acc2 = b2[t];
  for (int k=0;k<256;++k) acc2 += mid[k]*w2[k*256+t];
  out[b*HIDD + t] = acc2;
}

extern "C" void kernel_launch(void* const* d_in, const int* in_sizes, int n_in,
                              void* d_out, int out_size, void* d_ws, size_t ws_size,
                              hipStream_t stream)
{
  const float* x    = (const float*)d_in[0];
  const float* remb = (const float*)d_in[1];
  const float* ipw  = (const float*)d_in[2];
  const float* ipb  = (const float*)d_in[3];
  const float* gatw = (const float*)d_in[4];
  const float* asrc = (const float*)d_in[5];
  const float* adst = (const float*)d_in[6];
  const float* gatb = (const float*)d_in[7];
  const float* lng  = (const float*)d_in[8];
  const float* lnb  = (const float*)d_in[9];
  const float* row1 = (const float*)d_in[10];
  const float* rob1 = (const float*)d_in[11];
  const float* row2 = (const float*)d_in[12];
  const float* rob2 = (const float*)d_in[13];
  const int* ei   = (const int*)d_in[14];
  const int* batch= (const int*)d_in[15];
  const int* rid  = (const int*)d_in[16];

  char* ws = (char*)d_ws;
  int*   deg  = (int*)  (ws + 0);          // 200192
  int*   cur  = (int*)  (ws + 200192);     // 200192
  float* cnt  = (float*)(ws + 400384);     // 256
  float* pool = (float*)(ws + 400640);     // 16384
  // ZERO_BYTES = 417024
  int*   row  = (int*)  (ws + 417024);     // 200192
  int*   part = (int*)  (ws + 617216);     // 1024
  int*   csr  = (int*)  (ws + 618240);     // 1800192 -> 2418432
  float* ss   = (float*)(ws + 2418432);    // 800768
  float* sd   = (float*)(ws + 3219200);    // 800768  -> 4019968
  u16*   vmat = (u16*)  (ws + 4019968);    // 32768   -> 4052736
  u16*   feats= (u16*)  (ws + 4052736);    // 19218432-> 23271168
  u16*   wtin = (u16*)  (ws + 23271168);   // 98304   -> 23369472
  u16*   wtl  = (u16*)  (ws + 23369472);   // 524288  -> 23893760
  u16*   hA   = (u16*)  (ws + 23893760);   // 25624576-> 49518336
  u16*   hB   = (u16*)  (ws + 49518336);   // 25624576-> 75142912

  hipMemsetAsync(ws, 0, 417024, stream);

  k_setup <<<15550, 256, 0, stream>>>(x, remb, rid, feats, ipw, gatw, wtin, wtl,
                                      asrc, adst, vmat, ei, deg);
  k_scan1 <<<196, 256, 0, stream>>>(deg, row, part);
  k_scan23<<<196, 256, 0, stream>>>(row, part, 196);
  k_scatter<<<1758, 256, 0, stream>>>(ei, row, cur, csr);

  // input projection (bias, no scores): feats -> hA ; K=192
  k_gemm<KIN><<<dim3(391,2), 256, 0, stream>>>(feats, wtin, ipb, nullptr,
                                               nullptr, nullptr, hA, NN);

  for (int l = 0; l < 4; ++l){
    // layer GEMM: hA -> hB, MFMA-fused scores via vmat[l]; K=256
    k_gemm<HIDD><<<dim3(391,2), 256, 0, stream>>>(hA, wtl + (size_t)l*HIDD*HIDD, nullptr,
                                                  vmat + (size_t)l*16*256, ss, sd, hB, NN);
    k_aggregate<<<6250, 256, 0, stream>>>(hB, ss, sd, row, deg, csr,
                                          gatb + l*HIDD, lng + l*HIDD, lnb + l*HIDD, hA);
  }

  k_pool   <<<2000, 256, 0, stream>>>(hA, batch, pool, cnt);
  k_readout<<<16, 256, 0, stream>>>(pool, cnt, row1, rob1, row2, rob2, (float*)d_out);
}

// Round 15
// 467.676 us; speedup vs baseline: 1.1375x; 1.0478x over previous
//
#include <hip/hip_runtime.h>
#include <cmath>

typedef unsigned short u16;
typedef unsigned char u8;
typedef unsigned int u32;
typedef short bf16x8 __attribute__((ext_vector_type(8)));
typedef float f32x4 __attribute__((ext_vector_type(4)));
typedef float f32x2 __attribute__((ext_vector_type(2)));

#define NN 50000      // nodes
#define MP 50048      // padded to 128*391
#define EE 400000     // raw edges
#define ET 450000     // edges + self loops
#define HIDD 256
#define KIN 192       // 3*F
#define LN_EPSF 1e-5f

__device__ __forceinline__ float bf2f(u16 u){ return __uint_as_float(((u32)u)<<16); }
__device__ __forceinline__ u16 f2bf(float f){
  u32 x = __float_as_uint(f);
  u32 r = x + 0x7fffu + ((x>>16)&1u);   // RNE
  return (u16)(r>>16);
}
__device__ __forceinline__ u32 pack2(float a, float b){ return (u32)f2bf(a) | ((u32)f2bf(b)<<16); }
__device__ __forceinline__ u8 f2fp8(float v){
  return (u8)(__builtin_amdgcn_cvt_pk_fp8_f32(v, v, 0, false) & 0xff);  // OCP e4m3, RNE+sat
}

__device__ __forceinline__ void dma16(const u16* g, u16* lds){
  __builtin_amdgcn_global_load_lds(
      (const __attribute__((address_space(1))) void*)g,
      (__attribute__((address_space(3))) void*)lds, 16, 0, 0);
}

// ================ merged setup: feats | wt | vmat | degree (partitioned by block) ================
__global__ __launch_bounds__(256) void k_setup(
    const float* __restrict__ x, const float* __restrict__ remb, const int* __restrict__ rid,
    u16* __restrict__ feats,
    const float* __restrict__ ipw, const float* __restrict__ gatw,
    u16* __restrict__ wtin, u16* __restrict__ wtl,
    const float* __restrict__ asrc, const float* __restrict__ adst, u16* __restrict__ vmat,
    const int* __restrict__ ei, int* __restrict__ deg)
{
  int b = blockIdx.x;
  if (b < 12512){
    int e = b*768 + threadIdx.x;
    #pragma unroll
    for (int it=0; it<3; ++it, e+=256){
      int n = e / 192;
      int c = e - n*192;
      if (n >= MP) break;
      float v = 0.f;
      if (n < NN){
        if (c < 64){
          v = x[n*64 + c];
        } else if (c < 128){
          v = remb[rid[n]*64 + (c-64)];
        } else {
          int i = c - 128;
          float rate = exp2f(-(float)(2*(i>>1)) * (1.0f/64.0f) * 13.287712379549449f);
          float s, cc;
          sincosf((float)n * rate, &s, &cc);
          v = (i & 1) ? cc : s;
        }
      }
      feats[(size_t)n*192 + c] = f2bf(v);
    }
  } else if (b < 13728){
    int idx = (b - 12512)*256 + threadIdx.x;
    if (idx < 49152){               // inproj: [192][256] -> [256][192]
      int n = idx / 192, k = idx - n*192;
      wtin[idx] = f2bf(ipw[k*256 + n]);
    } else {
      int j = idx - 49152;          // gat: 4 x [256][256]^T
      if (j < 262144){
        int l = j >> 16, rem = j & 65535;
        int n = rem >> 8, k = rem & 255;
        wtl[j] = f2bf(gatw[l*65536 + k*256 + n]);
      }
    }
  } else if (b < 13792){
    // vmat[l][16][256]: rows 0..3 = W^T·a_src, 4..7 = W^T·a_dst, 8..15 zero
    int idx = (b - 13728)*256 + threadIdx.x;
    if (idx < 16384){
      int l = idx >> 12, rem = idx & 4095, v = rem >> 8, k = rem & 255;
      float s = 0.f;
      if (v < 8){
        const float* a = (v < 4) ? (asrc + l*256 + v*64) : (adst + l*256 + (v-4)*64);
        const float* w = gatw + (size_t)l*65536 + k*256 + (v & 3)*64;
        #pragma unroll 8
        for (int c=0;c<64;++c) s += w[c]*a[c];
      }
      vmat[idx] = f2bf(s);
    }
  } else {
    int i = (b - 13792)*256 + threadIdx.x;
    if (i < ET){
      int d = (i < EE) ? ei[EE + i] : (i - EE);
      atomicAdd(&deg[d], 1);
    }
  }
}

// ---------------- scan1: per-block exclusive scan + block totals ----------------
__global__ void k_scan1(const int* __restrict__ deg, int* __restrict__ row_off, int* __restrict__ part){
  __shared__ int s[256];
  int n = blockIdx.x*256 + threadIdx.x;
  int v = (n < NN) ? deg[n] : 0;
  s[threadIdx.x] = v;
  __syncthreads();
  for (int off=1; off<256; off<<=1){
    int t = (threadIdx.x >= off) ? s[threadIdx.x - off] : 0;
    __syncthreads();
    s[threadIdx.x] += t;
    __syncthreads();
  }
  if (n < NN) row_off[n] = s[threadIdx.x] - v;
  if (threadIdx.x == 255) part[blockIdx.x] = s[255];
}

// ---------------- scan23 ----------------
__global__ void k_scan23(int* __restrict__ row_off, const int* __restrict__ part, int nparts){
  __shared__ int sp[256];
  int t = threadIdx.x;
  sp[t] = (t < nparts && t < (int)blockIdx.x) ? part[t] : 0;
  __syncthreads();
  for (int off=128; off; off>>=1){
    if (t < off) sp[t] += sp[t+off];
    __syncthreads();
  }
  int n = blockIdx.x*256 + t;
  if (n < NN) row_off[n] += sp[0];
}

__global__ void k_scatter(const int* __restrict__ ei, const int* __restrict__ row_off,
                          int* __restrict__ cur, int* __restrict__ csr_src){
  int i = blockIdx.x*blockDim.x + threadIdx.x;
  if (i >= ET) return;
  int s, d;
  if (i < EE){ s = ei[i]; d = ei[EE + i]; } else { s = i - EE; d = i - EE; }
  int pos = row_off[d] + atomicAdd(&cur[d], 1);
  csr_src[pos] = s;
}

// ================ m97-style MFMA GEMM, double-buffered K-loop ================
// C[M][256](bf16) and/or C8[M][256](fp8 e4m3) = A[M][K](bf16) @ Wt[256][K]^T (+bias).
// grid (391,2). Per K-step: A 128x32 + B 128x32 via global_load_lds; stage(k+1)
// before compute(k); one barrier/step. Swizzle c = p ^ ((r>>2)&3) (2-way = free).
template<int K>
__global__ __launch_bounds__(256, 3) void k_gemm(
    const u16* __restrict__ A, const u16* __restrict__ Wt,
    const float* __restrict__ bias, const u16* __restrict__ vmat,
    float* __restrict__ ss, float* __restrict__ sd,
    u16* __restrict__ C, u8* __restrict__ C8, int M)
{
  __shared__ u16 Asl[2][128*32];   // 8 KB x2
  __shared__ u16 Bsl[2][128*32];   // 8 KB x2
  int tid = threadIdx.x;
  int wave = tid >> 6, lane = tid & 63, quad = lane >> 4, lm = lane & 15;
  int r0 = blockIdx.x * 128;
  int cb = blockIdx.y;                   // col half of C (0/1)
  int rW = (wave >> 1) * 64;
  int cW = (wave & 1) * 64;
  bool doScore = vmat && (cb == 0) && ((wave & 1) == 0);

  f32x4 acc[4][4] = {};
  f32x4 accs[4] = {};

  auto stage = [&](int buf, int k0){
    for (int m = wave; m < 8; m += 4){
      int s = m*64 + lane;
      int r = s >> 2, p = s & 3;
      int c = p ^ ((r >> 2) & 3);
      dma16(A + (size_t)(r0 + r)*K + k0 + c*8, &Asl[buf][m*512]);
    }
    for (int m = wave; m < 8; m += 4){
      int s = m*64 + lane;
      int r = s >> 2, p = s & 3;
      int c = p ^ ((r >> 2) & 3);
      dma16(Wt + (size_t)(cb*128 + r)*K + k0 + c*8, &Bsl[buf][m*512]);
    }
  };

  stage(0, 0);
  __syncthreads();

  for (int ks = 0; ks < K/32; ++ks){
    int cur = ks & 1;
    if (ks + 1 < K/32) stage(cur ^ 1, (ks+1)*32);

    bf16x8 a[4], b[4];
    #pragma unroll
    for (int i=0;i<4;++i){
      int row = rW + i*16 + lm;
      int slot = row*4 + (quad ^ ((row >> 2) & 3));
      a[i] = *(const bf16x8*)(&Asl[cur][slot*8]);
    }
    #pragma unroll
    for (int j=0;j<4;++j){
      int row = cW + j*16 + lm;
      int slot = row*4 + (quad ^ ((row >> 2) & 3));
      b[j] = *(const bf16x8*)(&Bsl[cur][slot*8]);
    }
    #pragma unroll
    for (int i=0;i<4;++i)
      #pragma unroll
      for (int j=0;j<4;++j)
        acc[i][j] = __builtin_amdgcn_mfma_f32_16x16x32_bf16(a[i], b[j], acc[i][j], 0, 0, 0);
    if (doScore){
      bf16x8 bs = *(const bf16x8*)(vmat + (size_t)lm*K + ks*32 + quad*8);
      #pragma unroll
      for (int i=0;i<4;++i)
        accs[i] = __builtin_amdgcn_mfma_f32_16x16x32_bf16(a[i], bs, accs[i], 0, 0, 0);
    }
    __syncthreads();   // drains next-step dma; protects cur buf before restage
  }

  // scores: C/D layout col=lane&15, row=quad*4+reg  [verified m89/m91]
  if (doScore){
    #pragma unroll
    for (int i=0;i<4;++i){
      #pragma unroll
      for (int r=0;r<4;++r){
        int row = r0 + rW + i*16 + quad*4 + r;
        if (row < M){
          if (lm < 4)      ss[row*4 + lm]     = accs[i][r];
          else if (lm < 8) sd[row*4 + lm - 4] = accs[i][r];
        }
      }
    }
  }

  // epilogue: direct stores (bf16 and/or fp8)
  #pragma unroll
  for (int i=0;i<4;++i){
    #pragma unroll
    for (int r=0;r<4;++r){
      int row = r0 + rW + i*16 + quad*4 + r;
      if (row < M){
        #pragma unroll
        for (int j=0;j<4;++j){
          int col = cb*128 + cW + j*16 + lm;
          float v = acc[i][j][r];
          if (bias) v += bias[col];
          if (C)  C[(size_t)row*256 + col] = f2bf(v);
          if (C8) C8[(size_t)row*256 + col] = f2fp8(v);
        }
      }
    }
  }
}

// ---------------- fused GAT aggregate + bias + relu + layernorm ----------------
// 2 nodes per wave (32 lanes x 8 ch), dual-chain; gathers fp8 e4m3 rows (256B),
// HW decode via v_cvt_pk_f32_fp8.
__global__ __launch_bounds__(256) void k_aggregate(
    const u8* __restrict__ h8, const float* __restrict__ ssrc, const float* __restrict__ sdst,
    const int* __restrict__ row_off, const int* __restrict__ deg, const int* __restrict__ csr_src,
    const float* __restrict__ bias, const float* __restrict__ g, const float* __restrict__ bb,
    u16* __restrict__ hout)
{
  int wv = (blockIdx.x*blockDim.x + threadIdx.x) >> 6;
  int lane = threadIdx.x & 63;
  int half = lane >> 5;
  int hl = lane & 31;
  int n = wv*2 + half;
  if (n >= NN) return;
  int c0 = hl*8;
  int head = hl >> 3;
  float sdh = sdst[n*4 + head];
  int ro = row_off[n];
  int dg = deg[n];
  float denA = 0.f, denB = 0.f;
  float a0=0,a1=0,a2=0,a3=0,a4=0,a5=0,a6=0,a7=0;
  float b0=0,b1=0,b2=0,b3=0,b4=0,b5=0,b6=0,b7=0;
  int j = 0;
  for (; j + 2 <= dg; j += 2){
    int sA = csr_src[ro+j];
    int sB = csr_src[ro+j+1];
    uint2 uA = *(const uint2*)(h8 + (size_t)sA*HIDD + c0);
    uint2 uB = *(const uint2*)(h8 + (size_t)sB*HIDD + c0);
    float eA = ssrc[sA*4+head] + sdh;
    float eB = ssrc[sB*4+head] + sdh;
    eA = (eA > 0.f) ? eA : 0.2f*eA;
    eB = (eB > 0.f) ? eB : 0.2f*eB;
    float xA = __expf(eA), xB = __expf(eB);
    denA += xA; denB += xB;
    f32x2 pA0 = __builtin_amdgcn_cvt_pk_f32_fp8((int)uA.x, false);
    f32x2 pA1 = __builtin_amdgcn_cvt_pk_f32_fp8((int)uA.x, true);
    f32x2 pA2 = __builtin_amdgcn_cvt_pk_f32_fp8((int)uA.y, false);
    f32x2 pA3 = __builtin_amdgcn_cvt_pk_f32_fp8((int)uA.y, true);
    f32x2 pB0 = __builtin_amdgcn_cvt_pk_f32_fp8((int)uB.x, false);
    f32x2 pB1 = __builtin_amdgcn_cvt_pk_f32_fp8((int)uB.x, true);
    f32x2 pB2 = __builtin_amdgcn_cvt_pk_f32_fp8((int)uB.y, false);
    f32x2 pB3 = __builtin_amdgcn_cvt_pk_f32_fp8((int)uB.y, true);
    a0 += xA*pA0.x; a1 += xA*pA0.y; a2 += xA*pA1.x; a3 += xA*pA1.y;
    a4 += xA*pA2.x; a5 += xA*pA2.y; a6 += xA*pA3.x; a7 += xA*pA3.y;
    b0 += xB*pB0.x; b1 += xB*pB0.y; b2 += xB*pB1.x; b3 += xB*pB1.y;
    b4 += xB*pB2.x; b5 += xB*pB2.y; b6 += xB*pB3.x; b7 += xB*pB3.y;
  }
  if (j < dg){
    int sA = csr_src[ro+j];
    uint2 uA = *(const uint2*)(h8 + (size_t)sA*HIDD + c0);
    float eA = ssrc[sA*4+head] + sdh;
    eA = (eA > 0.f) ? eA : 0.2f*eA;
    float xA = __expf(eA);
    denA += xA;
    f32x2 pA0 = __builtin_amdgcn_cvt_pk_f32_fp8((int)uA.x, false);
    f32x2 pA1 = __builtin_amdgcn_cvt_pk_f32_fp8((int)uA.x, true);
    f32x2 pA2 = __builtin_amdgcn_cvt_pk_f32_fp8((int)uA.y, false);
    f32x2 pA3 = __builtin_amdgcn_cvt_pk_f32_fp8((int)uA.y, true);
    a0 += xA*pA0.x; a1 += xA*pA0.y; a2 += xA*pA1.x; a3 += xA*pA1.y;
    a4 += xA*pA2.x; a5 += xA*pA2.y; a6 += xA*pA3.x; a7 += xA*pA3.y;
  }
  float inv = 1.f / (denA + denB);
  float y[8];
  y[0]=a0+b0; y[1]=a1+b1; y[2]=a2+b2; y[3]=a3+b3;
  y[4]=a4+b4; y[5]=a5+b5; y[6]=a6+b6; y[7]=a7+b7;
  float4 bi0 = *(const float4*)(bias + c0);
  float4 bi1 = *(const float4*)(bias + c0 + 4);
  y[0]=fmaxf(y[0]*inv+bi0.x,0.f); y[1]=fmaxf(y[1]*inv+bi0.y,0.f);
  y[2]=fmaxf(y[2]*inv+bi0.z,0.f); y[3]=fmaxf(y[3]*inv+bi0.w,0.f);
  y[4]=fmaxf(y[4]*inv+bi1.x,0.f); y[5]=fmaxf(y[5]*inv+bi1.y,0.f);
  y[6]=fmaxf(y[6]*inv+bi1.z,0.f); y[7]=fmaxf(y[7]*inv+bi1.w,0.f);
  // layernorm over 256 channels within the 32-lane half (xor-closed, offsets 1..16)
  float sum = (y[0]+y[1])+(y[2]+y[3])+((y[4]+y[5])+(y[6]+y[7]));
  #pragma unroll
  for (int o=16;o>=1;o>>=1) sum += __shfl_xor(sum, o);
  float mu = sum * (1.f/256.f);
  float d[8], sq = 0.f;
  #pragma unroll
  for (int k=0;k<8;++k){ d[k] = y[k]-mu; sq += d[k]*d[k]; }
  #pragma unroll
  for (int o=16;o>=1;o>>=1) sq += __shfl_xor(sq, o);
  float rs = rsqrtf(sq*(1.f/256.f) + LN_EPSF);
  float4 g0 = *(const float4*)(g + c0);
  float4 g1 = *(const float4*)(g + c0 + 4);
  float4 q0 = *(const float4*)(bb + c0);
  float4 q1 = *(const float4*)(bb + c0 + 4);
  uint4 o4;
  o4.x = pack2(d[0]*rs*g0.x + q0.x, d[1]*rs*g0.y + q0.y);
  o4.y = pack2(d[2]*rs*g0.z + q0.z, d[3]*rs*g0.w + q0.w);
  o4.z = pack2(d[4]*rs*g1.x + q1.x, d[5]*rs*g1.y + q1.y);
  o4.w = pack2(d[6]*rs*g1.z + q1.z, d[7]*rs*g1.w + q1.w);
  *(uint4*)(hout + (size_t)n*HIDD + c0) = o4;   // FIX: element offset (was c0*2)
}

// ---------------- global mean pool: 2000 blocks, run-length atomics (batch sorted) ----------------
__global__ __launch_bounds__(256) void k_pool(
    const u16* __restrict__ h, const int* __restrict__ batch,
    float* __restrict__ pooled, float* __restrict__ cnt)
{
  const int chunk = 25;  // 2000*25 >= NN
  int t = threadIdx.x;
  int n0 = blockIdx.x*chunk;
  int n1 = min(n0 + chunk, NN);
  if (n0 >= n1) return;
  float acc = 0.f;
  int curb = batch[n0];
  int runStart = n0;
  for (int n=n0; n<n1; ++n){
    int b = batch[n];
    if (b != curb){
      atomicAdd(&pooled[curb*HIDD + t], acc);
      if (t == 0) atomicAdd(&cnt[curb], (float)(n - runStart));
      acc = 0.f; curb = b; runStart = n;
    }
    acc += bf2f(h[(size_t)n*HIDD + t]);
  }
  atomicAdd(&pooled[curb*HIDD + t], acc);
  if (t == 0) atomicAdd(&cnt[curb], (float)(n1 - runStart));
}

// ---------------- readout: gelu(pooled@W1+b1)@W2+b2 (fp32, tiny) ----------------
__global__ __launch_bounds__(256) void k_readout(
    const float* __restrict__ pooled, const float* __restrict__ cnt,
    const float* __restrict__ w1, const float* __restrict__ b1,
    const float* __restrict__ w2, const float* __restrict__ b2,
    float* __restrict__ out)
{
  __shared__ float p[256], mid[256];
  int b = blockIdx.x, t = threadIdx.x;
  float c = fmaxf(cnt[b], 1.f);
  p[t] = pooled[b*HIDD + t] / c;
  __syncthreads();
  float acc = b1[t];
  for (int k=0;k<256;++k) acc += p[k]*w1[k*256+t];
  mid[t] = 0.5f*acc*(1.f + erff(acc*0.70710678118654752f));
  __syncthreads();
  float acc2 = b2[t];
  for (int k=0;k<256;++k) acc2 += mid[k]*w2[k*256+t];
  out[b*HIDD + t] = acc2;
}

extern "C" void kernel_launch(void* const* d_in, const int* in_sizes, int n_in,
                              void* d_out, int out_size, void* d_ws, size_t ws_size,
                              hipStream_t stream)
{
  const float* x    = (const float*)d_in[0];
  const float* remb = (const float*)d_in[1];
  const float* ipw  = (const float*)d_in[2];
  const float* ipb  = (const float*)d_in[3];
  const float* gatw = (const float*)d_in[4];
  const float* asrc = (const float*)d_in[5];
  const float* adst = (const float*)d_in[6];
  const float* gatb = (const float*)d_in[7];
  const float* lng  = (const float*)d_in[8];
  const float* lnb  = (const float*)d_in[9];
  const float* row1 = (const float*)d_in[10];
  const float* rob1 = (const float*)d_in[11];
  const float* row2 = (const float*)d_in[12];
  const float* rob2 = (const float*)d_in[13];
  const int* ei   = (const int*)d_in[14];
  const int* batch= (const int*)d_in[15];
  const int* rid  = (const int*)d_in[16];

  char* ws = (char*)d_ws;
  int*   deg  = (int*)  (ws + 0);          // 200192
  int*   cur  = (int*)  (ws + 200192);     // 200192
  float* cnt  = (float*)(ws + 400384);     // 256
  float* pool = (float*)(ws + 400640);     // 16384
  // ZERO_BYTES = 417024
  int*   row  = (int*)  (ws + 417024);     // 200192
  int*   part = (int*)  (ws + 617216);     // 1024
  int*   csr  = (int*)  (ws + 618240);     // 1800192 -> 2418432
  float* ss   = (float*)(ws + 2418432);    // 800768
  float* sd   = (float*)(ws + 3219200);    // 800768  -> 4019968
  u16*   vmat = (u16*)  (ws + 4019968);    // 32768   -> 4052736
  u16*   feats= (u16*)  (ws + 4052736);    // 19218432-> 23271168
  u16*   wtin = (u16*)  (ws + 23271168);   // 98304   -> 23369472
  u16*   wtl  = (u16*)  (ws + 23369472);   // 524288  -> 23893760
  u16*   hA   = (u16*)  (ws + 23893760);   // 25624576-> 49518336
  u8*    hB8  = (u8*)   (ws + 49518336);   // 12812288-> 62330624

  hipMemsetAsync(ws, 0, 417024, stream);

  k_setup <<<15550, 256, 0, stream>>>(x, remb, rid, feats, ipw, gatw, wtin, wtl,
                                      asrc, adst, vmat, ei, deg);
  k_scan1 <<<196, 256, 0, stream>>>(deg, row, part);
  k_scan23<<<196, 256, 0, stream>>>(row, part, 196);
  k_scatter<<<1758, 256, 0, stream>>>(ei, row, cur, csr);

  // input projection (bias, bf16 out only): feats -> hA ; K=192
  k_gemm<KIN><<<dim3(391,2), 256, 0, stream>>>(feats, wtin, ipb, nullptr,
                                               nullptr, nullptr, hA, nullptr, NN);

  for (int l = 0; l < 4; ++l){
    // layer GEMM: hA -> hB8 (fp8 only; bf16 h is dead), MFMA-fused scores via vmat[l]
    k_gemm<HIDD><<<dim3(391,2), 256, 0, stream>>>(hA, wtl + (size_t)l*HIDD*HIDD, nullptr,
                                                  vmat + (size_t)l*16*256, ss, sd,
                                                  nullptr, hB8, NN);
    k_aggregate<<<6250, 256, 0, stream>>>(hB8, ss, sd, row, deg, csr,
                                          gatb + l*HIDD, lng + l*HIDD, lnb + l*HIDD, hA);
  }

  k_pool   <<<2000, 256, 0, stream>>>(hA, batch, pool, cnt);
  k_readout<<<16, 256, 0, stream>>>(pool, cnt, row1, rob1, row2, rob2, (float*)d_out);
}

// Round 17
// 466.111 us; speedup vs baseline: 1.1413x; 1.0034x over previous
//
#include <hip/hip_runtime.h>
#include <cmath>

typedef unsigned short u16;
typedef unsigned char u8;
typedef unsigned int u32;
typedef short bf16x8 __attribute__((ext_vector_type(8)));
typedef float f32x4 __attribute__((ext_vector_type(4)));
typedef float f32x2 __attribute__((ext_vector_type(2)));

#define NN 50000      // nodes
#define MP 50048      // padded to 128*391
#define EE 400000     // raw edges
#define ET 450000     // edges + self loops
#define HIDD 256
#define KIN 192       // 3*F
#define LN_EPSF 1e-5f

__device__ __forceinline__ float bf2f(u16 u){ return __uint_as_float(((u32)u)<<16); }
__device__ __forceinline__ u16 f2bf(float f){
  u32 x = __float_as_uint(f);
  u32 r = x + 0x7fffu + ((x>>16)&1u);   // RNE
  return (u16)(r>>16);
}
__device__ __forceinline__ u32 pack2(float a, float b){ return (u32)f2bf(a) | ((u32)f2bf(b)<<16); }
__device__ __forceinline__ u8 f2fp8(float v){
  return (u8)(__builtin_amdgcn_cvt_pk_fp8_f32(v, v, 0, false) & 0xff);  // OCP e4m3, RNE+sat
}

__device__ __forceinline__ void dma16(const u16* g, u16* lds){
  __builtin_amdgcn_global_load_lds(
      (const __attribute__((address_space(1))) void*)g,
      (__attribute__((address_space(3))) void*)lds, 16, 0, 0);
}

// ================ merged setup: feats | wt | vmat | degree (partitioned by block) ================
__global__ __launch_bounds__(256) void k_setup(
    const float* __restrict__ x, const float* __restrict__ remb, const int* __restrict__ rid,
    u16* __restrict__ feats,
    const float* __restrict__ ipw, const float* __restrict__ gatw,
    u16* __restrict__ wtin, u16* __restrict__ wtl,
    const float* __restrict__ asrc, const float* __restrict__ adst, u16* __restrict__ vmat,
    const int* __restrict__ ei, int* __restrict__ deg)
{
  int b = blockIdx.x;
  if (b < 12512){
    int e = b*768 + threadIdx.x;
    #pragma unroll
    for (int it=0; it<3; ++it, e+=256){
      int n = e / 192;
      int c = e - n*192;
      if (n >= MP) break;
      float v = 0.f;
      if (n < NN){
        if (c < 64){
          v = x[n*64 + c];
        } else if (c < 128){
          v = remb[rid[n]*64 + (c-64)];
        } else {
          int i = c - 128;
          float rate = exp2f(-(float)(2*(i>>1)) * (1.0f/64.0f) * 13.287712379549449f);
          float s, cc;
          __sincosf((float)n * rate, &s, &cc);   // fast HW path; err ~3e-3 ~ bf16 rounding
          v = (i & 1) ? cc : s;
        }
      }
      feats[(size_t)n*192 + c] = f2bf(v);
    }
  } else if (b < 13728){
    int idx = (b - 12512)*256 + threadIdx.x;
    if (idx < 49152){               // inproj: [192][256] -> [256][192]
      int n = idx / 192, k = idx - n*192;
      wtin[idx] = f2bf(ipw[k*256 + n]);
    } else {
      int j = idx - 49152;          // gat: 4 x [256][256]^T
      if (j < 262144){
        int l = j >> 16, rem = j & 65535;
        int n = rem >> 8, k = rem & 255;
        wtl[j] = f2bf(gatw[l*65536 + k*256 + n]);
      }
    }
  } else if (b < 13792){
    // vmat[l][16][256]: rows 0..3 = W^T·a_src, 4..7 = W^T·a_dst, 8..15 zero
    int idx = (b - 13728)*256 + threadIdx.x;
    if (idx < 16384){
      int l = idx >> 12, rem = idx & 4095, v = rem >> 8, k = rem & 255;
      float s = 0.f;
      if (v < 8){
        const float* a = (v < 4) ? (asrc + l*256 + v*64) : (adst + l*256 + (v-4)*64);
        const float* w = gatw + (size_t)l*65536 + k*256 + (v & 3)*64;
        #pragma unroll 8
        for (int c=0;c<64;++c) s += w[c]*a[c];
      }
      vmat[idx] = f2bf(s);
    }
  } else {
    int i = (b - 13792)*256 + threadIdx.x;
    if (i < ET){
      int d = (i < EE) ? ei[EE + i] : (i - EE);
      atomicAdd(&deg[d], 1);
    }
  }
}

// ---------------- scan1: per-block exclusive scan + block totals ----------------
__global__ void k_scan1(const int* __restrict__ deg, int* __restrict__ row_off, int* __restrict__ part){
  __shared__ int s[256];
  int n = blockIdx.x*256 + threadIdx.x;
  int v = (n < NN) ? deg[n] : 0;
  s[threadIdx.x] = v;
  __syncthreads();
  for (int off=1; off<256; off<<=1){
    int t = (threadIdx.x >= off) ? s[threadIdx.x - off] : 0;
    __syncthreads();
    s[threadIdx.x] += t;
    __syncthreads();
  }
  if (n < NN) row_off[n] = s[threadIdx.x] - v;
  if (threadIdx.x == 255) part[blockIdx.x] = s[255];
}

// ---------------- scan23 ----------------
__global__ void k_scan23(int* __restrict__ row_off, const int* __restrict__ part, int nparts){
  __shared__ int sp[256];
  int t = threadIdx.x;
  sp[t] = (t < nparts && t < (int)blockIdx.x) ? part[t] : 0;
  __syncthreads();
  for (int off=128; off; off>>=1){
    if (t < off) sp[t] += sp[t+off];
    __syncthreads();
  }
  int n = blockIdx.x*256 + t;
  if (n < NN) row_off[n] += sp[0];
}

__global__ void k_scatter(const int* __restrict__ ei, const int* __restrict__ row_off,
                          int* __restrict__ cur, int* __restrict__ csr_src){
  int i = blockIdx.x*blockDim.x + threadIdx.x;
  if (i >= ET) return;
  int s, d;
  if (i < EE){ s = ei[i]; d = ei[EE + i]; } else { s = i - EE; d = i - EE; }
  int pos = row_off[d] + atomicAdd(&cur[d], 1);
  csr_src[pos] = s;
}

// ================ m97-style MFMA GEMM, double-buffered K-loop ================
// C[M][256](bf16) and/or C8[M][256](fp8 e4m3) = A[M][K](bf16) @ Wt[256][K]^T (+bias).
// grid (391,2). Per K-step: A 128x32 + B 128x32 via global_load_lds; stage(k+1)
// before compute(k); one barrier/step. Swizzle c = p ^ ((r>>2)&3) (2-way = free).
template<int K>
__global__ __launch_bounds__(256, 3) void k_gemm(
    const u16* __restrict__ A, const u16* __restrict__ Wt,
    const float* __restrict__ bias, const u16* __restrict__ vmat,
    float* __restrict__ ss, float* __restrict__ sd,
    u16* __restrict__ C, u8* __restrict__ C8, int M)
{
  __shared__ u16 Asl[2][128*32];   // 8 KB x2
  __shared__ u16 Bsl[2][128*32];   // 8 KB x2
  int tid = threadIdx.x;
  int wave = tid >> 6, lane = tid & 63, quad = lane >> 4, lm = lane & 15;
  int r0 = blockIdx.x * 128;
  int cb = blockIdx.y;                   // col half of C (0/1)
  int rW = (wave >> 1) * 64;
  int cW = (wave & 1) * 64;
  bool doScore = vmat && (cb == 0) && ((wave & 1) == 0);

  f32x4 acc[4][4] = {};
  f32x4 accs[4] = {};

  auto stage = [&](int buf, int k0){
    for (int m = wave; m < 8; m += 4){
      int s = m*64 + lane;
      int r = s >> 2, p = s & 3;
      int c = p ^ ((r >> 2) & 3);
      dma16(A + (size_t)(r0 + r)*K + k0 + c*8, &Asl[buf][m*512]);
    }
    for (int m = wave; m < 8; m += 4){
      int s = m*64 + lane;
      int r = s >> 2, p = s & 3;
      int c = p ^ ((r >> 2) & 3);
      dma16(Wt + (size_t)(cb*128 + r)*K + k0 + c*8, &Bsl[buf][m*512]);
    }
  };

  stage(0, 0);
  __syncthreads();

  for (int ks = 0; ks < K/32; ++ks){
    int cur = ks & 1;
    if (ks + 1 < K/32) stage(cur ^ 1, (ks+1)*32);

    bf16x8 a[4], b[4];
    #pragma unroll
    for (int i=0;i<4;++i){
      int row = rW + i*16 + lm;
      int slot = row*4 + (quad ^ ((row >> 2) & 3));
      a[i] = *(const bf16x8*)(&Asl[cur][slot*8]);
    }
    #pragma unroll
    for (int j=0;j<4;++j){
      int row = cW + j*16 + lm;
      int slot = row*4 + (quad ^ ((row >> 2) & 3));
      b[j] = *(const bf16x8*)(&Bsl[cur][slot*8]);
    }
    #pragma unroll
    for (int i=0;i<4;++i)
      #pragma unroll
      for (int j=0;j<4;++j)
        acc[i][j] = __builtin_amdgcn_mfma_f32_16x16x32_bf16(a[i], b[j], acc[i][j], 0, 0, 0);
    if (doScore){
      bf16x8 bs = *(const bf16x8*)(vmat + (size_t)lm*K + ks*32 + quad*8);
      #pragma unroll
      for (int i=0;i<4;++i)
        accs[i] = __builtin_amdgcn_mfma_f32_16x16x32_bf16(a[i], bs, accs[i], 0, 0, 0);
    }
    __syncthreads();   // drains next-step dma; protects cur buf before restage
  }

  // scores: C/D layout col=lane&15, row=quad*4+reg  [verified m89/m91]
  if (doScore){
    #pragma unroll
    for (int i=0;i<4;++i){
      #pragma unroll
      for (int r=0;r<4;++r){
        int row = r0 + rW + i*16 + quad*4 + r;
        if (row < M){
          if (lm < 4)      ss[row*4 + lm]     = accs[i][r];
          else if (lm < 8) sd[row*4 + lm - 4] = accs[i][r];
        }
      }
    }
  }

  // epilogue: direct stores (bf16 and/or fp8)
  #pragma unroll
  for (int i=0;i<4;++i){
    #pragma unroll
    for (int r=0;r<4;++r){
      int row = r0 + rW + i*16 + quad*4 + r;
      if (row < M){
        #pragma unroll
        for (int j=0;j<4;++j){
          int col = cb*128 + cW + j*16 + lm;
          float v = acc[i][j][r];
          if (bias) v += bias[col];
          if (C)  C[(size_t)row*256 + col] = f2bf(v);
          if (C8) C8[(size_t)row*256 + col] = f2fp8(v);
        }
      }
    }
  }
}

// ---------------- fused GAT aggregate + bias + relu + layernorm ----------------
// 2 nodes per wave (32 lanes x 8 ch), dual-chain; gathers fp8 e4m3 rows (256B),
// HW decode via v_cvt_pk_f32_fp8. Output: bf16 (hout) OR fp8 (hout8, final layer).
__global__ __launch_bounds__(256) void k_aggregate(
    const u8* __restrict__ h8, const float* __restrict__ ssrc, const float* __restrict__ sdst,
    const int* __restrict__ row_off, const int* __restrict__ deg, const int* __restrict__ csr_src,
    const float* __restrict__ bias, const float* __restrict__ g, const float* __restrict__ bb,
    u16* __restrict__ hout, u8* __restrict__ hout8)
{
  int wv = (blockIdx.x*blockDim.x + threadIdx.x) >> 6;
  int lane = threadIdx.x & 63;
  int half = lane >> 5;
  int hl = lane & 31;
  int n = wv*2 + half;
  if (n >= NN) return;
  int c0 = hl*8;
  int head = hl >> 3;
  float sdh = sdst[n*4 + head];
  int ro = row_off[n];
  int dg = deg[n];
  float denA = 0.f, denB = 0.f;
  float a0=0,a1=0,a2=0,a3=0,a4=0,a5=0,a6=0,a7=0;
  float b0=0,b1=0,b2=0,b3=0,b4=0,b5=0,b6=0,b7=0;
  int j = 0;
  for (; j + 2 <= dg; j += 2){
    int sA = csr_src[ro+j];
    int sB = csr_src[ro+j+1];
    uint2 uA = *(const uint2*)(h8 + (size_t)sA*HIDD + c0);
    uint2 uB = *(const uint2*)(h8 + (size_t)sB*HIDD + c0);
    float eA = ssrc[sA*4+head] + sdh;
    float eB = ssrc[sB*4+head] + sdh;
    eA = (eA > 0.f) ? eA : 0.2f*eA;
    eB = (eB > 0.f) ? eB : 0.2f*eB;
    float xA = __expf(eA), xB = __expf(eB);
    denA += xA; denB += xB;
    f32x2 pA0 = __builtin_amdgcn_cvt_pk_f32_fp8((int)uA.x, false);
    f32x2 pA1 = __builtin_amdgcn_cvt_pk_f32_fp8((int)uA.x, true);
    f32x2 pA2 = __builtin_amdgcn_cvt_pk_f32_fp8((int)uA.y, false);
    f32x2 pA3 = __builtin_amdgcn_cvt_pk_f32_fp8((int)uA.y, true);
    f32x2 pB0 = __builtin_amdgcn_cvt_pk_f32_fp8((int)uB.x, false);
    f32x2 pB1 = __builtin_amdgcn_cvt_pk_f32_fp8((int)uB.x, true);
    f32x2 pB2 = __builtin_amdgcn_cvt_pk_f32_fp8((int)uB.y, false);
    f32x2 pB3 = __builtin_amdgcn_cvt_pk_f32_fp8((int)uB.y, true);
    a0 += xA*pA0.x; a1 += xA*pA0.y; a2 += xA*pA1.x; a3 += xA*pA1.y;
    a4 += xA*pA2.x; a5 += xA*pA2.y; a6 += xA*pA3.x; a7 += xA*pA3.y;
    b0 += xB*pB0.x; b1 += xB*pB0.y; b2 += xB*pB1.x; b3 += xB*pB1.y;
    b4 += xB*pB2.x; b5 += xB*pB2.y; b6 += xB*pB3.x; b7 += xB*pB3.y;
  }
  if (j < dg){
    int sA = csr_src[ro+j];
    uint2 uA = *(const uint2*)(h8 + (size_t)sA*HIDD + c0);
    float eA = ssrc[sA*4+head] + sdh;
    eA = (eA > 0.f) ? eA : 0.2f*eA;
    float xA = __expf(eA);
    denA += xA;
    f32x2 pA0 = __builtin_amdgcn_cvt_pk_f32_fp8((int)uA.x, false);
    f32x2 pA1 = __builtin_amdgcn_cvt_pk_f32_fp8((int)uA.x, true);
    f32x2 pA2 = __builtin_amdgcn_cvt_pk_f32_fp8((int)uA.y, false);
    f32x2 pA3 = __builtin_amdgcn_cvt_pk_f32_fp8((int)uA.y, true);
    a0 += xA*pA0.x; a1 += xA*pA0.y; a2 += xA*pA1.x; a3 += xA*pA1.y;
    a4 += xA*pA2.x; a5 += xA*pA2.y; a6 += xA*pA3.x; a7 += xA*pA3.y;
  }
  float inv = 1.f / (denA + denB);
  float y[8];
  y[0]=a0+b0; y[1]=a1+b1; y[2]=a2+b2; y[3]=a3+b3;
  y[4]=a4+b4; y[5]=a5+b5; y[6]=a6+b6; y[7]=a7+b7;
  float4 bi0 = *(const float4*)(bias + c0);
  float4 bi1 = *(const float4*)(bias + c0 + 4);
  y[0]=fmaxf(y[0]*inv+bi0.x,0.f); y[1]=fmaxf(y[1]*inv+bi0.y,0.f);
  y[2]=fmaxf(y[2]*inv+bi0.z,0.f); y[3]=fmaxf(y[3]*inv+bi0.w,0.f);
  y[4]=fmaxf(y[4]*inv+bi1.x,0.f); y[5]=fmaxf(y[5]*inv+bi1.y,0.f);
  y[6]=fmaxf(y[6]*inv+bi1.z,0.f); y[7]=fmaxf(y[7]*inv+bi1.w,0.f);
  // layernorm over 256 channels within the 32-lane half (xor-closed, offsets 1..16)
  float sum = (y[0]+y[1])+(y[2]+y[3])+((y[4]+y[5])+(y[6]+y[7]));
  #pragma unroll
  for (int o=16;o>=1;o>>=1) sum += __shfl_xor(sum, o);
  float mu = sum * (1.f/256.f);
  float d[8], sq = 0.f;
  #pragma unroll
  for (int k=0;k<8;++k){ d[k] = y[k]-mu; sq += d[k]*d[k]; }
  #pragma unroll
  for (int o=16;o>=1;o>>=1) sq += __shfl_xor(sq, o);
  float rs = rsqrtf(sq*(1.f/256.f) + LN_EPSF);
  float4 g0 = *(const float4*)(g + c0);
  float4 g1 = *(const float4*)(g + c0 + 4);
  float4 q0 = *(const float4*)(bb + c0);
  float4 q1 = *(const float4*)(bb + c0 + 4);
  float o0 = d[0]*rs*g0.x + q0.x, o1 = d[1]*rs*g0.y + q0.y;
  float o2 = d[2]*rs*g0.z + q0.z, o3 = d[3]*rs*g0.w + q0.w;
  float o4v= d[4]*rs*g1.x + q1.x, o5 = d[5]*rs*g1.y + q1.y;
  float o6 = d[6]*rs*g1.z + q1.z, o7 = d[7]*rs*g1.w + q1.w;
  if (hout8){
    u32 w0 = (u32)__builtin_amdgcn_cvt_pk_fp8_f32(o0, o1, 0, false);
    w0 = (u32)__builtin_amdgcn_cvt_pk_fp8_f32(o2, o3, (int)w0, true);
    u32 w1 = (u32)__builtin_amdgcn_cvt_pk_fp8_f32(o4v, o5, 0, false);
    w1 = (u32)__builtin_amdgcn_cvt_pk_fp8_f32(o6, o7, (int)w1, true);
    uint2 o8; o8.x = w0; o8.y = w1;
    *(uint2*)(hout8 + (size_t)n*HIDD + c0) = o8;
  } else {
    uint4 o4;
    o4.x = pack2(o0, o1);
    o4.y = pack2(o2, o3);
    o4.z = pack2(o4v, o5);
    o4.w = pack2(o6, o7);
    *(uint4*)(hout + (size_t)n*HIDD + c0) = o4;
  }
}

// ---------------- global mean pool (fp8 input): 2000 blocks, run-length atomics ----------------
__global__ __launch_bounds__(256) void k_pool(
    const u8* __restrict__ h8, const int* __restrict__ batch,
    float* __restrict__ pooled, float* __restrict__ cnt)
{
  const int chunk = 25;  // 2000*25 >= NN
  int t = threadIdx.x;
  int n0 = blockIdx.x*chunk;
  int n1 = min(n0 + chunk, NN);
  if (n0 >= n1) return;
  float acc = 0.f;
  int curb = batch[n0];
  int runStart = n0;
  bool hi = (t & 2) != 0;
  for (int n=n0; n<n1; ++n){
    int b = batch[n];
    if (b != curb){
      atomicAdd(&pooled[curb*HIDD + t], acc);
      if (t == 0) atomicAdd(&cnt[curb], (float)(n - runStart));
      acc = 0.f; curb = b; runStart = n;
    }
    u32 w = *(const u32*)(h8 + (size_t)n*HIDD + (t & ~3));
    f32x2 p = hi ? __builtin_amdgcn_cvt_pk_f32_fp8((int)w, true)
                 : __builtin_amdgcn_cvt_pk_f32_fp8((int)w, false);  // word-sel must be const
    acc += (t & 1) ? p.y : p.x;
  }
  atomicAdd(&pooled[curb*HIDD + t], acc);
  if (t == 0) atomicAdd(&cnt[curb], (float)(n1 - runStart));
}

// ---------------- readout: gelu(pooled@W1+b1)@W2+b2 (fp32, tiny) ----------------
__global__ __launch_bounds__(256) void k_readout(
    const float* __restrict__ pooled, const float* __restrict__ cnt,
    const float* __restrict__ w1, const float* __restrict__ b1,
    const float* __restrict__ w2, const float* __restrict__ b2,
    float* __restrict__ out)
{
  __shared__ float p[256], mid[256];
  int b = blockIdx.x, t = threadIdx.x;
  float c = fmaxf(cnt[b], 1.f);
  p[t] = pooled[b*HIDD + t] / c;
  __syncthreads();
  float acc = b1[t];
  for (int k=0;k<256;++k) acc += p[k]*w1[k*256+t];
  mid[t] = 0.5f*acc*(1.f + erff(acc*0.70710678118654752f));
  __syncthreads();
  float acc2 = b2[t];
  for (int k=0;k<256;++k) acc2 += mid[k]*w2[k*256+t];
  out[b*HIDD + t] = acc2;
}

extern "C" void kernel_launch(void* const* d_in, const int* in_sizes, int n_in,
                              void* d_out, int out_size, void* d_ws, size_t ws_size,
                              hipStream_t stream)
{
  const float* x    = (const float*)d_in[0];
  const float* remb = (const float*)d_in[1];
  const float* ipw  = (const float*)d_in[2];
  const float* ipb  = (const float*)d_in[3];
  const float* gatw = (const float*)d_in[4];
  const float* asrc = (const float*)d_in[5];
  const float* adst = (const float*)d_in[6];
  const float* gatb = (const float*)d_in[7];
  const float* lng  = (const float*)d_in[8];
  const float* lnb  = (const float*)d_in[9];
  const float* row1 = (const float*)d_in[10];
  const float* rob1 = (const float*)d_in[11];
  const float* row2 = (const float*)d_in[12];
  const float* rob2 = (const float*)d_in[13];
  const int* ei   = (const int*)d_in[14];
  const int* batch= (const int*)d_in[15];
  const int* rid  = (const int*)d_in[16];

  char* ws = (char*)d_ws;
  int*   deg  = (int*)  (ws + 0);          // 200192
  int*   cur  = (int*)  (ws + 200192);     // 200192
  float* cnt  = (float*)(ws + 400384);     // 256
  float* pool = (float*)(ws + 400640);     // 16384
  // ZERO_BYTES = 417024
  int*   row  = (int*)  (ws + 417024);     // 200192
  int*   part = (int*)  (ws + 617216);     // 1024
  int*   csr  = (int*)  (ws + 618240);     // 1800192 -> 2418432
  float* ss   = (float*)(ws + 2418432);    // 800768
  float* sd   = (float*)(ws + 3219200);    // 800768  -> 4019968
  u16*   vmat = (u16*)  (ws + 4019968);    // 32768   -> 4052736
  u16*   feats= (u16*)  (ws + 4052736);    // 19218432-> 23271168
  u16*   wtin = (u16*)  (ws + 23271168);   // 98304   -> 23369472
  u16*   wtl  = (u16*)  (ws + 23369472);   // 524288  -> 23893760
  u16*   hA   = (u16*)  (ws + 23893760);   // 25624576-> 49518336  (bf16 h / fp8 final)
  u8*    hA8  = (u8*)   (ws + 23893760);   // alias: final-layer fp8 h
  u8*    hB8  = (u8*)   (ws + 49518336);   // 12812288-> 62330624

  (void)hipMemsetAsync(ws, 0, 417024, stream);

  k_setup <<<15550, 256, 0, stream>>>(x, remb, rid, feats, ipw, gatw, wtin, wtl,
                                      asrc, adst, vmat, ei, deg);
  k_scan1 <<<196, 256, 0, stream>>>(deg, row, part);
  k_scan23<<<196, 256, 0, stream>>>(row, part, 196);
  k_scatter<<<1758, 256, 0, stream>>>(ei, row, cur, csr);

  // input projection (bias, bf16 out only): feats -> hA ; K=192
  k_gemm<KIN><<<dim3(391,2), 256, 0, stream>>>(feats, wtin, ipb, nullptr,
                                               nullptr, nullptr, hA, nullptr, NN);

  for (int l = 0; l < 4; ++l){
    // layer GEMM: hA -> hB8 (fp8), MFMA-fused scores via vmat[l]
    k_gemm<HIDD><<<dim3(391,2), 256, 0, stream>>>(hA, wtl + (size_t)l*HIDD*HIDD, nullptr,
                                                  vmat + (size_t)l*16*256, ss, sd,
                                                  nullptr, hB8, NN);
    if (l < 3){
      k_aggregate<<<6250, 256, 0, stream>>>(hB8, ss, sd, row, deg, csr,
                                            gatb + l*HIDD, lng + l*HIDD, lnb + l*HIDD,
                                            hA, nullptr);
    } else {
      // final layer: write fp8 (pool decodes) — halves pool read + agg write traffic
      k_aggregate<<<6250, 256, 0, stream>>>(hB8, ss, sd, row, deg, csr,
                                            gatb + l*HIDD, lng + l*HIDD, lnb + l*HIDD,
                                            nullptr, hA8);
    }
  }

  k_pool   <<<2000, 256, 0, stream>>>(hA8, batch, pool, cnt);
  k_readout<<<16, 256, 0, stream>>>(pool, cnt, row1, rob1, row2, rob2, (float*)d_out);
}